// Round 4
// baseline (14.064 us; speedup 1.0000x reference)
//
#include <hip/hip_runtime.h>

#define GRID_H 128
#define GRID_W 128
#define N_POS  8192
#define NBLOCKS 8
#define NTHREADS 1024
#define EPS_F  1e-12f
#define MAGIC  0x5CA1AB1Eu

__global__ __launch_bounds__(NTHREADS) void MazeCollision_kernel(
    const float* __restrict__ pos,   // [N_POS, 2]
    const float* __restrict__ maze,  // [GRID_H, GRID_W]
    const float* __restrict__ rad_p, // [1]
    float* __restrict__ out,         // [1]
    float* __restrict__ vals,        // d_ws + 0      : block partials
    unsigned int* __restrict__ flags)// d_ws + 256 B  : ready flags
{
    __shared__ float smaze[GRID_H * GRID_W];  // 64 KiB
    const int t = threadIdx.x;
    const int bid = blockIdx.x;

    // Stage maze -> LDS: 4 x float4 per thread, coalesced.
    {
        const float4* m4 = (const float4*)maze;
        float4* s4 = (float4*)smaze;
        #pragma unroll
        for (int k = 0; k < (GRID_H * GRID_W / 4) / NTHREADS; ++k)
            s4[t + k * NTHREADS] = m4[t + k * NTHREADS];
    }
    const float rad = rad_p[0];
    const float2 xy = ((const float2*)pos)[bid * NTHREADS + t];
    const float x = xy.x, y = xy.y;
    __syncthreads();

    float acc = 0.0f;
    if (rad <= 1.5f) {
        // Contributing rows: i in (x-2, x+1) -> at most 3 ints, covered by
        // {floor(x)-1, floor(x), floor(x)+1}. Clamping the window ORIGIN to
        // [0, DIM-3] keeps it fully in-bounds; rows/cols shifted in lie
        // >= 1.5 from the position => contribute exactly 0. Branchless.
        const int i0 = min(max((int)floorf(x) - 1, 0), GRID_H - 3);
        const int j0 = min(max((int)floorf(y) - 1, 0), GRID_W - 3);
        float dy2[3];
        #pragma unroll
        for (int c = 0; c < 3; ++c) {
            const float dy = y - ((float)(j0 + c) + 0.5f);
            dy2[c] = dy * dy;
        }
        const int base = i0 * GRID_W + j0;
        #pragma unroll
        for (int r = 0; r < 3; ++r) {
            const float dx = x - ((float)(i0 + r) + 0.5f);
            const float dx2 = dx * dx;
            #pragma unroll
            for (int c = 0; c < 3; ++c) {
                const float occ = smaze[base + r * GRID_W + c];
                const float d = __builtin_amdgcn_sqrtf(fmaxf(dx2 + dy2[c], EPS_F));
                acc += fmaxf(rad - d, 0.0f) * occ;
            }
        }
    } else {
        // General-radius fallback (not exercised at rad = 1.5).
        const int ilo = max(0, (int)floorf(x - 0.5f - rad));
        const int ihi = min(GRID_H - 1, (int)ceilf(x - 0.5f + rad));
        const int jlo = max(0, (int)floorf(y - 0.5f - rad));
        const int jhi = min(GRID_W - 1, (int)ceilf(y - 0.5f + rad));
        for (int i = ilo; i <= ihi; ++i) {
            const float dx = x - ((float)i + 0.5f);
            const float dx2 = dx * dx;
            for (int j = jlo; j <= jhi; ++j) {
                const float dyv = y - ((float)j + 0.5f);
                const float d = sqrtf(fmaxf(dx2 + dyv * dyv, EPS_F));
                acc += fmaxf(rad - d, 0.0f) * smaze[i * GRID_W + j];
            }
        }
    }

    // wave (64-lane) reduction
    #pragma unroll
    for (int off = 32; off > 0; off >>= 1)
        acc += __shfl_down(acc, off, 64);

    __shared__ float wsum[NTHREADS / 64];   // 16 wave partials
    if ((t & 63) == 0) wsum[t >> 6] = acc;
    __syncthreads();

    if (t < NTHREADS / 64) {                // 16 lanes of wave 0
        float v = wsum[t];
        #pragma unroll
        for (int off = 8; off > 0; off >>= 1)
            v += __shfl_down(v, off, 64);   // lane 0 = block sum

        if (bid != 0) {
            if (t == 0) {
                __hip_atomic_store(&vals[bid], v, __ATOMIC_RELAXED, __HIP_MEMORY_SCOPE_AGENT);
                __hip_atomic_store(&flags[bid], MAGIC, __ATOMIC_RELEASE, __HIP_MEMORY_SCOPE_AGENT);
            }
        } else {
            float g = 0.0f;
            if (t == 0) g = v;
            if (t >= 1 && t < NBLOCKS) {
                while (__hip_atomic_load(&flags[t], __ATOMIC_ACQUIRE, __HIP_MEMORY_SCOPE_AGENT) != MAGIC) {}
                g = __hip_atomic_load(&vals[t], __ATOMIC_RELAXED, __HIP_MEMORY_SCOPE_AGENT);
                // reset for next replay (first call sees 0xAA poison != MAGIC)
                __hip_atomic_store(&flags[t], 0u, __ATOMIC_RELAXED, __HIP_MEMORY_SCOPE_AGENT);
            }
            #pragma unroll
            for (int off = 4; off > 0; off >>= 1)
                g += __shfl_down(g, off, 64);
            if (t == 0) out[0] = g;         // deterministic plain store
        }
    }
}

extern "C" void kernel_launch(void* const* d_in, const int* in_sizes, int n_in,
                              void* d_out, int out_size, void* d_ws, size_t ws_size,
                              hipStream_t stream) {
    const float* pos  = (const float*)d_in[0];
    const float* maze = (const float*)d_in[1];
    const float* rad  = (const float*)d_in[2];
    float* out = (float*)d_out;
    float* vals = (float*)d_ws;
    unsigned int* flags = (unsigned int*)((char*)d_ws + 256);

    MazeCollision_kernel<<<NBLOCKS, NTHREADS, 0, stream>>>(pos, maze, rad, out, vals, flags);
}

// Round 5
// 11.783 us; speedup vs baseline: 1.1936x; 1.1936x over previous
//
#include <hip/hip_runtime.h>

#define GRID_H 128
#define GRID_W 128
#define N_POS  8192
#define NBLOCKS 8
#define NTHREADS 1024
#define EPS_F  1e-12f
#define MAGIC  0x5CA1AB1Eu

__global__ __launch_bounds__(NTHREADS) void MazeCollision_kernel(
    const float* __restrict__ pos,   // [N_POS, 2]
    const float* __restrict__ maze,  // [GRID_H, GRID_W]
    const float* __restrict__ rad_p, // [1]
    float* __restrict__ out,         // [1]
    float* __restrict__ vals,        // d_ws + 0      : block partials
    unsigned int* __restrict__ flags)// d_ws + 256 B  : ready flags
{
    const int t = threadIdx.x;
    const int bid = blockIdx.x;
    const float rad = rad_p[0];

    const float2 xy = ((const float2*)pos)[bid * NTHREADS + t];
    const float x = xy.x, y = xy.y;

    float acc = 0.0f;
    if (rad <= 1.5f) {
        // Contributing rows: i in (x-2, x+1) -> at most 3 ints, covered by
        // {floor(x)-1, floor(x), floor(x)+1} (cells at exactly d=rad give 0).
        // Clamping the window ORIGIN to [0, DIM-3] keeps it fully in-bounds;
        // rows/cols shifted in lie >= 1.5 away => contribute exactly 0.
        // Branchless, no masks; reads hit L1/L2 (maze is 64 KB, cache-hot).
        const int i0 = min(max((int)floorf(x) - 1, 0), GRID_H - 3);
        const int j0 = min(max((int)floorf(y) - 1, 0), GRID_W - 3);
        float dy2[3];
        #pragma unroll
        for (int c = 0; c < 3; ++c) {
            const float dy = y - ((float)(j0 + c) + 0.5f);
            dy2[c] = dy * dy;
        }
        const float* w = maze + i0 * GRID_W + j0;
        #pragma unroll
        for (int r = 0; r < 3; ++r) {
            const float dx = x - ((float)(i0 + r) + 0.5f);
            const float dx2 = dx * dx;
            #pragma unroll
            for (int c = 0; c < 3; ++c) {
                const float occ = w[r * GRID_W + c];
                const float d = __builtin_amdgcn_sqrtf(fmaxf(dx2 + dy2[c], EPS_F));
                acc += fmaxf(rad - d, 0.0f) * occ;
            }
        }
    } else {
        // General-radius fallback (not exercised at rad = 1.5).
        const int ilo = max(0, (int)floorf(x - 0.5f - rad));
        const int ihi = min(GRID_H - 1, (int)ceilf(x - 0.5f + rad));
        const int jlo = max(0, (int)floorf(y - 0.5f - rad));
        const int jhi = min(GRID_W - 1, (int)ceilf(y - 0.5f + rad));
        for (int i = ilo; i <= ihi; ++i) {
            const float dx = x - ((float)i + 0.5f);
            const float dx2 = dx * dx;
            for (int j = jlo; j <= jhi; ++j) {
                const float dyv = y - ((float)j + 0.5f);
                const float d = sqrtf(fmaxf(dx2 + dyv * dyv, EPS_F));
                acc += fmaxf(rad - d, 0.0f) * maze[i * GRID_W + j];
            }
        }
    }

    // wave (64-lane) reduction
    #pragma unroll
    for (int off = 32; off > 0; off >>= 1)
        acc += __shfl_down(acc, off, 64);

    __shared__ float wsum[NTHREADS / 64];   // 16 wave partials
    if ((t & 63) == 0) wsum[t >> 6] = acc;
    __syncthreads();

    if (t < NTHREADS / 64) {                // 16 lanes of wave 0
        float v = wsum[t];
        #pragma unroll
        for (int off = 8; off > 0; off >>= 1)
            v += __shfl_down(v, off, 64);   // lane 0 = block sum

        if (bid != 0) {
            if (t == 0) {
                __hip_atomic_store(&vals[bid], v, __ATOMIC_RELAXED, __HIP_MEMORY_SCOPE_AGENT);
                __hip_atomic_store(&flags[bid], MAGIC, __ATOMIC_RELEASE, __HIP_MEMORY_SCOPE_AGENT);
            }
        } else {
            float g = 0.0f;
            if (t == 0) g = v;
            if (t >= 1 && t < NBLOCKS) {
                while (__hip_atomic_load(&flags[t], __ATOMIC_ACQUIRE, __HIP_MEMORY_SCOPE_AGENT) != MAGIC) {}
                g = __hip_atomic_load(&vals[t], __ATOMIC_RELAXED, __HIP_MEMORY_SCOPE_AGENT);
                // reset for next replay (first call sees 0xAA poison != MAGIC)
                __hip_atomic_store(&flags[t], 0u, __ATOMIC_RELAXED, __HIP_MEMORY_SCOPE_AGENT);
            }
            #pragma unroll
            for (int off = 4; off > 0; off >>= 1)
                g += __shfl_down(g, off, 64);
            if (t == 0) out[0] = g;         // deterministic plain store
        }
    }
}

extern "C" void kernel_launch(void* const* d_in, const int* in_sizes, int n_in,
                              void* d_out, int out_size, void* d_ws, size_t ws_size,
                              hipStream_t stream) {
    const float* pos  = (const float*)d_in[0];
    const float* maze = (const float*)d_in[1];
    const float* rad  = (const float*)d_in[2];
    float* out = (float*)d_out;
    float* vals = (float*)d_ws;
    unsigned int* flags = (unsigned int*)((char*)d_ws + 256);

    MazeCollision_kernel<<<NBLOCKS, NTHREADS, 0, stream>>>(pos, maze, rad, out, vals, flags);
}